// Round 1
// baseline (121.750 us; speedup 1.0000x reference)
//
#include <hip/hip_runtime.h>

#define K_DIM 64
#define N_DIM 4096

typedef float  f4   __attribute__((ext_vector_type(4)));
typedef short  s8v  __attribute__((ext_vector_type(8)));

// fp32 -> bf16 bits, round-to-nearest-even (inputs are uniform [0,1]; no NaN path)
static __device__ __forceinline__ unsigned short f2bf(float f) {
    unsigned int u = __builtin_bit_cast(unsigned int, f);
    u = (u + 0x7fffu + ((u >> 16) & 1u)) >> 16;
    return (unsigned short)u;
}

// Phase 0: zero row_sums + out, extract diag(X)
__global__ void init_kernel(const float* __restrict__ X, float* __restrict__ rs,
                            float* __restrict__ diag, float* __restrict__ out) {
    int gid = blockIdx.x * 256 + threadIdx.x;
    if (gid < K_DIM * N_DIM) rs[gid] = 0.f;
    if (gid < N_DIM) diag[gid] = X[gid * (N_DIM + 1)];
    if (gid == 0) *out = 0.f;
}

// Phase 1: row_sums[k,i] += sum_n zs[k,n] * X[i,n]  (bf16 MFMA, fp32 accum)
// grid: (16 n-chunks of 256, 32 i-tiles of 128), block 256 = 4 waves.
// Wave w owns k-range [16w, 16w+16); 8 B-frag tiles cover 128 i.
__global__ __launch_bounds__(256, 2) void gemm_rs_kernel(
    const float* __restrict__ zs, const float* __restrict__ X,
    float* __restrict__ rs) {
    // LDS tiles stored pre-swizzled: one 16B packet per lane per MFMA tile,
    // so fragment loads are dense conflict-free ds_read_b128.
    __shared__ s8v zs_l[16 * 64];  // 4 kb x 4 nb tiles (A operand), 16 KB
    __shared__ s8v x_l [32 * 64];  // 8 ibl x 4 nb tiles (B operand), 32 KB

    const int tid  = threadIdx.x;
    const int lane = tid & 63;
    const int w    = tid >> 6;
    const int i0   = blockIdx.y * 128;
    const int nb0  = blockIdx.x * 256;

    f4 acc[8] = {};

    for (int sc = 0; sc < 2; ++sc) {
        const int nsub = nb0 + sc * 128;

        // stage zs sub-chunk: 64 k x 128 n = 1024 packets of 8 elems
        #pragma unroll
        for (int it = 0; it < 4; ++it) {
            int p = tid + it * 256;
            int k = p >> 4, q = p & 15;
            const float* g = zs + k * N_DIM + nsub + q * 8;
            f4 f0 = *(const f4*)g;
            f4 f1 = *(const f4*)(g + 4);
            s8v h;
            h[0] = (short)f2bf(f0[0]); h[1] = (short)f2bf(f0[1]);
            h[2] = (short)f2bf(f0[2]); h[3] = (short)f2bf(f0[3]);
            h[4] = (short)f2bf(f1[0]); h[5] = (short)f2bf(f1[1]);
            h[6] = (short)f2bf(f1[2]); h[7] = (short)f2bf(f1[3]);
            int kb = k >> 4, nb = q >> 2;
            int dl = ((kb * 4 + nb) << 6) | (k & 15) | ((q & 3) << 4);
            zs_l[dl] = h;
        }
        // stage X sub-chunk: 128 i x 128 n = 2048 packets
        #pragma unroll
        for (int it = 0; it < 8; ++it) {
            int p = tid + it * 256;
            int il = p >> 4, q = p & 15;
            const float* g = X + (i0 + il) * N_DIM + nsub + q * 8;
            f4 f0 = *(const f4*)g;
            f4 f1 = *(const f4*)(g + 4);
            s8v h;
            h[0] = (short)f2bf(f0[0]); h[1] = (short)f2bf(f0[1]);
            h[2] = (short)f2bf(f0[2]); h[3] = (short)f2bf(f0[3]);
            h[4] = (short)f2bf(f1[0]); h[5] = (short)f2bf(f1[1]);
            h[6] = (short)f2bf(f1[2]); h[7] = (short)f2bf(f1[3]);
            int ibl = il >> 4, nb = q >> 2;
            int dl = ((ibl * 4 + nb) << 6) | (il & 15) | ((q & 3) << 4);
            x_l[dl] = h;
        }
        __syncthreads();

        #pragma unroll
        for (int nb = 0; nb < 4; ++nb) {
            s8v a = zs_l[((w * 4 + nb) << 6) | lane];
            #pragma unroll
            for (int ibl = 0; ibl < 8; ++ibl) {
                s8v b = x_l[((ibl * 4 + nb) << 6) | lane];
                acc[ibl] = __builtin_amdgcn_mfma_f32_16x16x32_bf16(a, b, acc[ibl], 0, 0, 0);
            }
        }
        __syncthreads();
    }

    // C/D layout (m89-verified): col = lane&15, row = (lane>>4)*4 + reg
    const int krow = w * 16 + ((lane >> 4) << 2);
    const int icol = i0 + (lane & 15);
    #pragma unroll
    for (int ibl = 0; ibl < 8; ++ibl) {
        #pragma unroll
        for (int r = 0; r < 4; ++r) {
            atomicAdd(&rs[(krow + r) * N_DIM + icol + ibl * 16], acc[ibl][r]);
        }
    }
}

// Phase 2: exact-fp32 epilogue + full reduction to scalar
__global__ void epilogue_kernel(const float* __restrict__ rs,
                                const float* __restrict__ zs,
                                const float* __restrict__ diag,
                                const float* __restrict__ varp,
                                float* __restrict__ out) {
    const float var = *varp;
    const int tid = threadIdx.x;
    float sum = 0.f;
    for (int idx = blockIdx.x * 256 + tid; idx < K_DIM * N_DIM; idx += gridDim.x * 256) {
        int i = idx & (N_DIM - 1);
        float z   = zs[idx];
        float num = z * diag[i];
        float den = rs[idx] - num;
        sum += num / (var + den);
    }
    #pragma unroll
    for (int off = 32; off >= 1; off >>= 1) sum += __shfl_down(sum, off);
    __shared__ float wsum[4];
    if ((tid & 63) == 0) wsum[tid >> 6] = sum;
    __syncthreads();
    if (tid == 0)
        atomicAdd(out, -(wsum[0] + wsum[1] + wsum[2] + wsum[3]) * (1.0f / 64.0f));
}

extern "C" void kernel_launch(void* const* d_in, const int* in_sizes, int n_in,
                              void* d_out, int out_size, void* d_ws, size_t ws_size,
                              hipStream_t stream) {
    const float* zs   = (const float*)d_in[0];
    const float* X    = (const float*)d_in[1];
    const float* varp = (const float*)d_in[2];
    float* out  = (float*)d_out;
    float* rs   = (float*)d_ws;                 // 64*4096 floats = 1 MB
    float* diag = rs + K_DIM * N_DIM;           // 4096 floats

    hipLaunchKernelGGL(init_kernel, dim3(1024), dim3(256), 0, stream, X, rs, diag, out);
    hipLaunchKernelGGL(gemm_rs_kernel, dim3(16, 32), dim3(256), 0, stream, zs, X, rs);
    hipLaunchKernelGGL(epilogue_kernel, dim3(256), dim3(256), 0, stream, rs, zs, diag, varp, out);
}